// Round 1
// baseline (303.958 us; speedup 1.0000x reference)
//
#include <hip/hip_runtime.h>

// SGLayerEpilogue: noise-add -> LeakyReLU(0.2) -> PixelNorm(over C) ->
// InstanceNorm(over HW) -> StyleMod(linear scale/shift)
// B=16, C=512, H=W=64, S=512. All fp32.

#define BB 16
#define CC 512
#define HWN 4096          // H*W
#define HW4 1024          // HW / 4 (float4 units)
#define KSPLIT 64         // channel-split blocks for pixel-norm partial sums
#define CPB (CC / KSPLIT) // 8 channels per partial block

#define EPS_PIXEL 1e-8f
#define EPS_INST 1e-5f

// ---------------------------------------------------------------------------
// Kernel A: s_lin[b, j] = style[b,:] @ lin_W[:, j] + lin_b[j],  j in [0, 2C)
// ---------------------------------------------------------------------------
__global__ void style_gemm(const float* __restrict__ style,
                           const float* __restrict__ lin_W,
                           const float* __restrict__ lin_b,
                           float* __restrict__ s_lin) {
    const int b = blockIdx.x;
    const int j = blockIdx.y * 256 + threadIdx.x;
    __shared__ float ssty[512];
    ssty[threadIdx.x]       = style[b * 512 + threadIdx.x];
    ssty[threadIdx.x + 256] = style[b * 512 + 256 + threadIdx.x];
    __syncthreads();
    float acc = lin_b[j];
#pragma unroll 8
    for (int k = 0; k < 512; ++k)
        acc = fmaf(ssty[k], lin_W[k * 1024 + j], acc);
    s_lin[b * 1024 + j] = acc;
}

// ---------------------------------------------------------------------------
// Kernel 1: per-pixel partial sum of y^2 over an 8-channel slab.
// partial[(b*KSPLIT + cs) * HWN + hw]  (lives in d_out, reused as scratch)
// ---------------------------------------------------------------------------
__global__ void pixel_partial(const float* __restrict__ x,
                              const float* __restrict__ noise,
                              const float* __restrict__ nw,
                              float* __restrict__ partial) {
    const int bid = blockIdx.x;     // 0 .. B*KSPLIT-1
    const int b  = bid >> 6;        // / KSPLIT
    const int cs = bid & 63;        // % KSPLIT
    const int c0 = cs * CPB;
    const int t = threadIdx.x;

    const float4* x4 = (const float4*)x;
    const float4* n4 = (const float4*)noise + (size_t)b * HW4;

    float4 nz[4], acc[4];
#pragma unroll
    for (int i = 0; i < 4; ++i) {
        nz[i] = n4[t + 256 * i];
        acc[i] = make_float4(0.f, 0.f, 0.f, 0.f);
    }

#pragma unroll
    for (int cci = 0; cci < CPB; ++cci) {
        const int c = c0 + cci;
        const float w = nw[c];
        const float4* xp = x4 + (size_t)(b * CC + c) * HW4;
#pragma unroll
        for (int i = 0; i < 4; ++i) {
            float4 v = xp[t + 256 * i];
            float y0 = fmaf(w, nz[i].x, v.x); y0 = fmaxf(y0, 0.2f * y0);
            float y1 = fmaf(w, nz[i].y, v.y); y1 = fmaxf(y1, 0.2f * y1);
            float y2 = fmaf(w, nz[i].z, v.z); y2 = fmaxf(y2, 0.2f * y2);
            float y3 = fmaf(w, nz[i].w, v.w); y3 = fmaxf(y3, 0.2f * y3);
            acc[i].x = fmaf(y0, y0, acc[i].x);
            acc[i].y = fmaf(y1, y1, acc[i].y);
            acc[i].z = fmaf(y2, y2, acc[i].z);
            acc[i].w = fmaf(y3, y3, acc[i].w);
        }
    }

    float4* pp = (float4*)partial + (size_t)(b * KSPLIT + cs) * HW4;
#pragma unroll
    for (int i = 0; i < 4; ++i)
        pp[t + 256 * i] = acc[i];
}

// ---------------------------------------------------------------------------
// Kernel 1b: fold KSPLIT partials -> r[b,hw] = rsqrt(mean_c(y^2) + eps)
// ---------------------------------------------------------------------------
__global__ void pixel_reduce(const float* __restrict__ partial,
                             float* __restrict__ rbuf) {
    const int g = blockIdx.x * 256 + threadIdx.x;  // 0 .. B*HW4-1
    const int b = g >> 10;
    const int q = g & 1023;
    const float4* p4 = (const float4*)partial;
    float4 s = make_float4(0.f, 0.f, 0.f, 0.f);
#pragma unroll 8
    for (int k = 0; k < KSPLIT; ++k) {
        float4 v = p4[(size_t)(b * KSPLIT + k) * HW4 + q];
        s.x += v.x; s.y += v.y; s.z += v.z; s.w += v.w;
    }
    const float inv_c = 1.0f / (float)CC;
    float4 o;
    o.x = rsqrtf(fmaf(s.x, inv_c, EPS_PIXEL));
    o.y = rsqrtf(fmaf(s.y, inv_c, EPS_PIXEL));
    o.z = rsqrtf(fmaf(s.z, inv_c, EPS_PIXEL));
    o.w = rsqrtf(fmaf(s.w, inv_c, EPS_PIXEL));
    ((float4*)rbuf)[g] = o;
}

// ---------------------------------------------------------------------------
// Kernel 2: fused InstanceNorm + StyleMod.
// One block per (b,c) plane (4096 px). z = y*r kept in registers across the
// stats reduction; out = z*A + Bias with A = istd*(s0+1), Bias = s1 - m*A.
// ---------------------------------------------------------------------------
__global__ void fused_apply(const float* __restrict__ x,
                            const float* __restrict__ noise,
                            const float* __restrict__ nw,
                            const float* __restrict__ rbuf,
                            const float* __restrict__ s_lin,
                            float* __restrict__ out) {
    const int bid = blockIdx.x;     // 0 .. B*C-1
    const int b = bid >> 9;
    const int c = bid & 511;
    const int t = threadIdx.x;
    const float w = nw[c];

    const float4* x4 = (const float4*)x + (size_t)(b * CC + c) * HW4;
    const float4* n4 = (const float4*)noise + (size_t)b * HW4;
    const float4* r4 = (const float4*)rbuf + (size_t)b * HW4;

    float4 z[4];
    float sum = 0.f, sum2 = 0.f;
#pragma unroll
    for (int i = 0; i < 4; ++i) {
        const int q = t + 256 * i;
        float4 v = x4[q];
        float4 nz = n4[q];
        float4 rr = r4[q];
        float y0 = fmaf(w, nz.x, v.x); y0 = fmaxf(y0, 0.2f * y0);
        float y1 = fmaf(w, nz.y, v.y); y1 = fmaxf(y1, 0.2f * y1);
        float y2 = fmaf(w, nz.z, v.z); y2 = fmaxf(y2, 0.2f * y2);
        float y3 = fmaf(w, nz.w, v.w); y3 = fmaxf(y3, 0.2f * y3);
        float4 zz;
        zz.x = y0 * rr.x; zz.y = y1 * rr.y; zz.z = y2 * rr.z; zz.w = y3 * rr.w;
        z[i] = zz;
        sum  += zz.x + zz.y + zz.z + zz.w;
        sum2 = fmaf(zz.x, zz.x, sum2);
        sum2 = fmaf(zz.y, zz.y, sum2);
        sum2 = fmaf(zz.z, zz.z, sum2);
        sum2 = fmaf(zz.w, zz.w, sum2);
    }

    // block reduce (4 waves of 64)
    __shared__ float lds[16];
#pragma unroll
    for (int off = 32; off > 0; off >>= 1) {
        sum  += __shfl_down(sum, off, 64);
        sum2 += __shfl_down(sum2, off, 64);
    }
    const int lane = t & 63, wv = t >> 6;
    if (lane == 0) { lds[wv] = sum; lds[8 + wv] = sum2; }
    __syncthreads();
    if (t == 0) {
        float S1 = lds[0] + lds[1] + lds[2] + lds[3];
        float S2 = lds[8] + lds[9] + lds[10] + lds[11];
        float m = S1 * (1.0f / (float)HWN);
        float var = fmaf(-m, m, S2 * (1.0f / (float)HWN));
        float istd = rsqrtf(var + EPS_INST);
        float s0 = s_lin[b * 1024 + c];
        float s1 = s_lin[b * 1024 + 512 + c];
        float A = istd * (s0 + 1.0f);
        lds[12] = A;
        lds[13] = fmaf(-m, A, s1);
    }
    __syncthreads();
    const float A = lds[12];
    const float Bs = lds[13];

    float4* o4 = (float4*)out + (size_t)(b * CC + c) * HW4;
#pragma unroll
    for (int i = 0; i < 4; ++i) {
        const int q = t + 256 * i;
        float4 zz = z[i];
        float4 o;
        o.x = fmaf(zz.x, A, Bs);
        o.y = fmaf(zz.y, A, Bs);
        o.z = fmaf(zz.z, A, Bs);
        o.w = fmaf(zz.w, A, Bs);
        o4[q] = o;
    }
}

// ---------------------------------------------------------------------------
extern "C" void kernel_launch(void* const* d_in, const int* in_sizes, int n_in,
                              void* d_out, int out_size, void* d_ws, size_t ws_size,
                              hipStream_t stream) {
    const float* x      = (const float*)d_in[0];  // [16,512,64,64]
    const float* noise  = (const float*)d_in[1];  // [16,1,64,64]
    const float* style  = (const float*)d_in[2];  // [16,512]
    const float* nw     = (const float*)d_in[3];  // [512]
    const float* lin_W  = (const float*)d_in[4];  // [512,1024]
    const float* lin_b  = (const float*)d_in[5];  // [1024]
    float* out = (float*)d_out;
    float* ws  = (float*)d_ws;

    float* s_lin = ws;            // 16384 floats
    float* rbuf  = ws + 16384;    // 65536 floats
    // Reuse d_out (134 MB) as scratch for the 16 MB partial-sum array; it is
    // fully consumed by pixel_reduce before fused_apply overwrites d_out.
    float* partial = out;

    style_gemm<<<dim3(BB, 4), 256, 0, stream>>>(style, lin_W, lin_b, s_lin);
    pixel_partial<<<BB * KSPLIT, 256, 0, stream>>>(x, noise, nw, partial);
    pixel_reduce<<<(BB * HW4) / 256, 256, 0, stream>>>(partial, rbuf);
    fused_apply<<<BB * CC, 256, 0, stream>>>(x, noise, nw, rbuf, s_lin, out);
}

// Round 2
// 266.051 us; speedup vs baseline: 1.1425x; 1.1425x over previous
//
#include <hip/hip_runtime.h>

// SGLayerEpilogue: noise-add -> LeakyReLU(0.2) -> PixelNorm(over C) ->
// InstanceNorm(over HW) -> StyleMod(linear scale/shift)
// B=16, C=512, H=W=64, S=512. All fp32.

#define BB 16
#define CC 512
#define HWN 4096          // H*W
#define HW4 1024          // HW / 4 (float4 units)
#define KSPLIT 64         // channel-split blocks for pixel-norm partial sums
#define CPB (CC / KSPLIT) // 8 channels per partial block
#define NSTYLE 256        // style partial blocks: 16 b x 4 jgroup x 4 kchunk

#define EPS_PIXEL 1e-8f
#define EPS_INST 1e-5f

// ---------------------------------------------------------------------------
// K1: merged grid.
//   blocks [0, NSTYLE): style-GEMM partials, K split 4 ways.
//       sp[(b*4 + z)*1024 + j] = (z==0 ? lin_b[j] : 0) + sum_{k in chunk z}
//                                 style[b,k] * lin_W[k,j]
//   blocks [NSTYLE, NSTYLE + B*KSPLIT): per-pixel partial sums of y^2 over an
//       8-channel slab -> partial[(b*KSPLIT+cs)*HWN + hw]  (lives in d_out).
// Style blocks come FIRST so their latency-bound FMA chains get scheduled
// early and hide under the memory-bound x streaming of the pixel blocks.
// ---------------------------------------------------------------------------
__global__ __launch_bounds__(256) void k1_partials(
        const float* __restrict__ x,
        const float* __restrict__ noise,
        const float* __restrict__ nw,
        const float* __restrict__ style,
        const float* __restrict__ lin_W,
        const float* __restrict__ lin_b,
        float* __restrict__ partial,
        float* __restrict__ sp) {
    const int bid = blockIdx.x;
    const int t = threadIdx.x;

    if (bid < NSTYLE) {
        // ---- style GEMM partial ----
        const int b  = bid >> 4;        // / 16
        const int jg = (bid >> 2) & 3;  // j group (256 cols each)
        const int z  = bid & 3;         // k chunk (128 rows each)
        const int j  = jg * 256 + t;
        __shared__ float ssty[128];
        if (t < 128) ssty[t] = style[b * 512 + z * 128 + t];
        __syncthreads();
        float acc = (z == 0) ? lin_b[j] : 0.0f;
        const float* Wp = lin_W + (size_t)(z * 128) * 1024 + j;
#pragma unroll 8
        for (int k = 0; k < 128; ++k)
            acc = fmaf(ssty[k], Wp[(size_t)k * 1024], acc);
        sp[(size_t)(b * 4 + z) * 1024 + j] = acc;
        return;
    }

    // ---- pixel-norm partial ----
    const int pb = bid - NSTYLE;    // 0 .. B*KSPLIT-1
    const int b  = pb >> 6;         // / KSPLIT
    const int cs = pb & 63;         // % KSPLIT
    const int c0 = cs * CPB;

    const float4* x4 = (const float4*)x;
    const float4* n4 = (const float4*)noise + (size_t)b * HW4;

    float4 nz[4], acc[4];
#pragma unroll
    for (int i = 0; i < 4; ++i) {
        nz[i] = n4[t + 256 * i];
        acc[i] = make_float4(0.f, 0.f, 0.f, 0.f);
    }

#pragma unroll
    for (int cci = 0; cci < CPB; ++cci) {
        const int c = c0 + cci;
        const float w = nw[c];
        const float4* xp = x4 + (size_t)(b * CC + c) * HW4;
#pragma unroll
        for (int i = 0; i < 4; ++i) {
            float4 v = xp[t + 256 * i];
            float y0 = fmaf(w, nz[i].x, v.x); y0 = fmaxf(y0, 0.2f * y0);
            float y1 = fmaf(w, nz[i].y, v.y); y1 = fmaxf(y1, 0.2f * y1);
            float y2 = fmaf(w, nz[i].z, v.z); y2 = fmaxf(y2, 0.2f * y2);
            float y3 = fmaf(w, nz[i].w, v.w); y3 = fmaxf(y3, 0.2f * y3);
            acc[i].x = fmaf(y0, y0, acc[i].x);
            acc[i].y = fmaf(y1, y1, acc[i].y);
            acc[i].z = fmaf(y2, y2, acc[i].z);
            acc[i].w = fmaf(y3, y3, acc[i].w);
        }
    }

    float4* pp = (float4*)partial + (size_t)(b * KSPLIT + cs) * HW4;
#pragma unroll
    for (int i = 0; i < 4; ++i)
        pp[t + 256 * i] = acc[i];
}

// ---------------------------------------------------------------------------
// K2: fold KSPLIT partials -> r[b,hw] = rsqrt(mean_c(y^2) + eps)
// 4-way K-split per block + LDS fold: 256 blocks, 16-deep load chains.
// ---------------------------------------------------------------------------
__global__ __launch_bounds__(256) void pixel_reduce(
        const float* __restrict__ partial,
        float* __restrict__ rbuf) {
    const int bid = blockIdx.x;       // 0 .. 255
    const int b  = bid >> 4;          // / 16
    const int qb = (bid & 15) * 64;   // float4-index base within [0,1024)
    const int t = threadIdx.x;
    const int ql = t & 63;            // which float4 output
    const int kq = t >> 6;            // which k quarter

    const float4* p4 = (const float4*)partial;
    float4 s = make_float4(0.f, 0.f, 0.f, 0.f);
    const int q = qb + ql;
#pragma unroll
    for (int kk = 0; kk < 16; ++kk) {
        const int k = kq * 16 + kk;
        float4 v = p4[(size_t)(b * KSPLIT + k) * HW4 + q];
        s.x += v.x; s.y += v.y; s.z += v.z; s.w += v.w;
    }
    __shared__ float4 red[256];
    red[t] = s;
    __syncthreads();
    if (t < 64) {
        float4 a0 = red[t], a1 = red[t + 64], a2 = red[t + 128], a3 = red[t + 192];
        float sx = a0.x + a1.x + a2.x + a3.x;
        float sy = a0.y + a1.y + a2.y + a3.y;
        float sz = a0.z + a1.z + a2.z + a3.z;
        float sw = a0.w + a1.w + a2.w + a3.w;
        const float inv_c = 1.0f / (float)CC;
        float4 o;
        o.x = rsqrtf(fmaf(sx, inv_c, EPS_PIXEL));
        o.y = rsqrtf(fmaf(sy, inv_c, EPS_PIXEL));
        o.z = rsqrtf(fmaf(sz, inv_c, EPS_PIXEL));
        o.w = rsqrtf(fmaf(sw, inv_c, EPS_PIXEL));
        ((float4*)rbuf)[b * HW4 + qb + t] = o;
    }
}

// ---------------------------------------------------------------------------
// K3: fused InstanceNorm + StyleMod.
// One block per (b,c) plane (4096 px). z = y*r kept in registers across the
// stats reduction; out = z*A + Bias with A = istd*(s0+1), Bias = s1 - m*A.
// Style scale/shift folded from the 4 K-chunk partials by the block leader.
// ---------------------------------------------------------------------------
__global__ __launch_bounds__(256) void fused_apply(
        const float* __restrict__ x,
        const float* __restrict__ noise,
        const float* __restrict__ nw,
        const float* __restrict__ rbuf,
        const float* __restrict__ sp,
        float* __restrict__ out) {
    const int bid = blockIdx.x;     // 0 .. B*C-1
    const int b = bid >> 9;
    const int c = bid & 511;
    const int t = threadIdx.x;
    const float w = nw[c];

    // Leader prefetches style partials early to hide L2 latency.
    float s0p = 0.f, s1p = 0.f;
    if (t == 0) {
#pragma unroll
        for (int z = 0; z < 4; ++z) {
            s0p += sp[(size_t)(b * 4 + z) * 1024 + c];
            s1p += sp[(size_t)(b * 4 + z) * 1024 + 512 + c];
        }
    }

    const float4* x4 = (const float4*)x + (size_t)(b * CC + c) * HW4;
    const float4* n4 = (const float4*)noise + (size_t)b * HW4;
    const float4* r4 = (const float4*)rbuf + (size_t)b * HW4;

    float4 zv[4];
    float sum = 0.f, sum2 = 0.f;
#pragma unroll
    for (int i = 0; i < 4; ++i) {
        const int q = t + 256 * i;
        float4 v = x4[q];
        float4 nz = n4[q];
        float4 rr = r4[q];
        float y0 = fmaf(w, nz.x, v.x); y0 = fmaxf(y0, 0.2f * y0);
        float y1 = fmaf(w, nz.y, v.y); y1 = fmaxf(y1, 0.2f * y1);
        float y2 = fmaf(w, nz.z, v.z); y2 = fmaxf(y2, 0.2f * y2);
        float y3 = fmaf(w, nz.w, v.w); y3 = fmaxf(y3, 0.2f * y3);
        float4 zz;
        zz.x = y0 * rr.x; zz.y = y1 * rr.y; zz.z = y2 * rr.z; zz.w = y3 * rr.w;
        zv[i] = zz;
        sum  += zz.x + zz.y + zz.z + zz.w;
        sum2 = fmaf(zz.x, zz.x, sum2);
        sum2 = fmaf(zz.y, zz.y, sum2);
        sum2 = fmaf(zz.z, zz.z, sum2);
        sum2 = fmaf(zz.w, zz.w, sum2);
    }

    // block reduce (4 waves of 64)
    __shared__ float lds[16];
#pragma unroll
    for (int off = 32; off > 0; off >>= 1) {
        sum  += __shfl_down(sum, off, 64);
        sum2 += __shfl_down(sum2, off, 64);
    }
    const int lane = t & 63, wv = t >> 6;
    if (lane == 0) { lds[wv] = sum; lds[8 + wv] = sum2; }
    __syncthreads();
    if (t == 0) {
        float S1 = lds[0] + lds[1] + lds[2] + lds[3];
        float S2 = lds[8] + lds[9] + lds[10] + lds[11];
        float m = S1 * (1.0f / (float)HWN);
        float var = fmaf(-m, m, S2 * (1.0f / (float)HWN));
        float istd = rsqrtf(var + EPS_INST);
        float A = istd * (s0p + 1.0f);
        lds[12] = A;
        lds[13] = fmaf(-m, A, s1p);
    }
    __syncthreads();
    const float A = lds[12];
    const float Bs = lds[13];

    float4* o4 = (float4*)out + (size_t)(b * CC + c) * HW4;
#pragma unroll
    for (int i = 0; i < 4; ++i) {
        const int q = t + 256 * i;
        float4 zz = zv[i];
        float4 o;
        o.x = fmaf(zz.x, A, Bs);
        o.y = fmaf(zz.y, A, Bs);
        o.z = fmaf(zz.z, A, Bs);
        o.w = fmaf(zz.w, A, Bs);
        o4[q] = o;
    }
}

// ---------------------------------------------------------------------------
extern "C" void kernel_launch(void* const* d_in, const int* in_sizes, int n_in,
                              void* d_out, int out_size, void* d_ws, size_t ws_size,
                              hipStream_t stream) {
    const float* x      = (const float*)d_in[0];  // [16,512,64,64]
    const float* noise  = (const float*)d_in[1];  // [16,1,64,64]
    const float* style  = (const float*)d_in[2];  // [16,512]
    const float* nw     = (const float*)d_in[3];  // [512]
    const float* lin_W  = (const float*)d_in[4];  // [512,1024]
    const float* lin_b  = (const float*)d_in[5];  // [1024]
    float* out = (float*)d_out;
    float* ws  = (float*)d_ws;

    float* sp   = ws;             // style partials: 16*4*1024 = 65536 floats
    float* rbuf = ws + 65536;     // 16*4096 = 65536 floats
    // Reuse d_out (134 MB) as scratch for the 16 MB partial-sum array; it is
    // fully consumed by pixel_reduce before fused_apply overwrites d_out.
    float* partial = out;

    k1_partials<<<NSTYLE + BB * KSPLIT, 256, 0, stream>>>(
        x, noise, nw, style, lin_W, lin_b, partial, sp);
    pixel_reduce<<<256, 256, 0, stream>>>(partial, rbuf);
    fused_apply<<<BB * CC, 256, 0, stream>>>(x, noise, nw, rbuf, sp, out);
}

// Round 3
// 257.884 us; speedup vs baseline: 1.1787x; 1.0317x over previous
//
#include <hip/hip_runtime.h>

// SGLayerEpilogue: noise-add -> LeakyReLU(0.2) -> PixelNorm(over C) ->
// InstanceNorm(over HW) -> StyleMod(linear scale/shift)
// B=16, C=512, H=W=64, S=512. All fp32.

#define BB 16
#define CC 512
#define HWN 4096          // H*W
#define HW4 1024          // HW / 4 (float4 units)
#define NSTYLE 256        // style partial blocks: 16 b x 4 jgroup x 4 kchunk
#define NPIX (BB * 64)    // pixel blocks: 64 px per block, 64 chunks per b

#define EPS_PIXEL 1e-8f
#define EPS_INST 1e-5f

typedef float vf4 __attribute__((ext_vector_type(4)));

// ---------------------------------------------------------------------------
// K1: merged grid.
//   blocks [0, NSTYLE): style-GEMM partials, K split 4 ways.
//       sp[(b*4 + z)*1024 + j] = (z==0 ? lin_b[j] : 0) + sum_{k in chunk z}
//                                 style[b,k] * lin_W[k,j]
//   blocks [NSTYLE, NSTYLE + NPIX): per-pixel sum of y^2 over ALL channels.
//       Block owns 64 pixels; thread t: pixel = t&63, channel group = t>>6
//       (128 channels each). LDS-fold the 4 groups -> rbuf[b,hw] =
//       rsqrt(mean_c(y^2) + eps) written directly (no partial round-trip).
// Style blocks come FIRST so their latency-bound FMA chains hide under the
// memory-bound x streaming of the pixel blocks.
// ---------------------------------------------------------------------------
__global__ __launch_bounds__(256) void k1_stats(
        const float* __restrict__ x,
        const float* __restrict__ noise,
        const float* __restrict__ nw,
        const float* __restrict__ style,
        const float* __restrict__ lin_W,
        const float* __restrict__ lin_b,
        float* __restrict__ rbuf,
        float* __restrict__ sp) {
    const int bid = blockIdx.x;
    const int t = threadIdx.x;

    if (bid < NSTYLE) {
        // ---- style GEMM partial ----
        const int b  = bid >> 4;        // / 16
        const int jg = (bid >> 2) & 3;  // j group (256 cols each)
        const int z  = bid & 3;         // k chunk (128 rows each)
        const int j  = jg * 256 + t;
        __shared__ float ssty[128];
        if (t < 128) ssty[t] = style[b * 512 + z * 128 + t];
        __syncthreads();
        float acc = (z == 0) ? lin_b[j] : 0.0f;
        const float* Wp = lin_W + (size_t)(z * 128) * 1024 + j;
#pragma unroll 8
        for (int k = 0; k < 128; ++k)
            acc = fmaf(ssty[k], Wp[(size_t)k * 1024], acc);
        sp[(size_t)(b * 4 + z) * 1024 + j] = acc;
        return;
    }

    // ---- per-pixel channel reduction ----
    const int pb  = bid - NSTYLE;     // 0 .. NPIX-1
    const int b   = pb >> 6;          // / 64
    const int hw0 = (pb & 63) * 64;   // pixel chunk base
    const int p   = t & 63;           // pixel within chunk
    const int g   = t >> 6;           // channel group (128 ch each)

    __shared__ float snw[CC];
    snw[t] = nw[t];
    snw[t + 256] = nw[t + 256];
    __syncthreads();

    const float nz = noise[b * HWN + hw0 + p];
    const float* xp = x + ((size_t)(b * CC + g * 128) * HWN) + hw0 + p;

    float acc = 0.0f;
#pragma unroll 8
    for (int k = 0; k < 128; ++k) {
        float v = xp[(size_t)k * HWN];
        float w = snw[g * 128 + k];
        float y = fmaf(w, nz, v);
        y = fmaxf(y, 0.2f * y);
        acc = fmaf(y, y, acc);
    }

    __shared__ float red[256];
    red[t] = acc;
    __syncthreads();
    if (t < 64) {
        float s = red[t] + red[t + 64] + red[t + 128] + red[t + 192];
        rbuf[b * HWN + hw0 + t] = rsqrtf(fmaf(s, 1.0f / (float)CC, EPS_PIXEL));
    }
}

// ---------------------------------------------------------------------------
// K2: fused InstanceNorm + StyleMod.
// One block per (b,c) plane (4096 px). z = y*r kept in registers across the
// stats reduction; out = z*A + Bias with A = istd*(s0+1), Bias = s1 - m*A.
// Style scale/shift folded from the 4 K-chunk partials by the block leader.
// out written with nontemporal stores so the 134 MB stream doesn't evict x
// (which this kernel is concurrently re-reading) from the Infinity Cache.
// ---------------------------------------------------------------------------
__global__ __launch_bounds__(256) void fused_apply(
        const float* __restrict__ x,
        const float* __restrict__ noise,
        const float* __restrict__ nw,
        const float* __restrict__ rbuf,
        const float* __restrict__ sp,
        float* __restrict__ out) {
    const int bid = blockIdx.x;     // 0 .. B*C-1
    const int b = bid >> 9;
    const int c = bid & 511;
    const int t = threadIdx.x;
    const float w = nw[c];

    // Leader prefetches style partials early to hide L2 latency.
    float s0p = 0.f, s1p = 0.f;
    if (t == 0) {
#pragma unroll
        for (int z = 0; z < 4; ++z) {
            s0p += sp[(size_t)(b * 4 + z) * 1024 + c];
            s1p += sp[(size_t)(b * 4 + z) * 1024 + 512 + c];
        }
    }

    const float4* x4 = (const float4*)x + (size_t)(b * CC + c) * HW4;
    const float4* n4 = (const float4*)noise + (size_t)b * HW4;
    const float4* r4 = (const float4*)rbuf + (size_t)b * HW4;

    float4 zv[4];
    float sum = 0.f, sum2 = 0.f;
#pragma unroll
    for (int i = 0; i < 4; ++i) {
        const int q = t + 256 * i;
        float4 v = x4[q];
        float4 nz = n4[q];
        float4 rr = r4[q];
        float y0 = fmaf(w, nz.x, v.x); y0 = fmaxf(y0, 0.2f * y0);
        float y1 = fmaf(w, nz.y, v.y); y1 = fmaxf(y1, 0.2f * y1);
        float y2 = fmaf(w, nz.z, v.z); y2 = fmaxf(y2, 0.2f * y2);
        float y3 = fmaf(w, nz.w, v.w); y3 = fmaxf(y3, 0.2f * y3);
        float4 zz;
        zz.x = y0 * rr.x; zz.y = y1 * rr.y; zz.z = y2 * rr.z; zz.w = y3 * rr.w;
        zv[i] = zz;
        sum  += zz.x + zz.y + zz.z + zz.w;
        sum2 = fmaf(zz.x, zz.x, sum2);
        sum2 = fmaf(zz.y, zz.y, sum2);
        sum2 = fmaf(zz.z, zz.z, sum2);
        sum2 = fmaf(zz.w, zz.w, sum2);
    }

    // block reduce (4 waves of 64)
    __shared__ float lds[16];
#pragma unroll
    for (int off = 32; off > 0; off >>= 1) {
        sum  += __shfl_down(sum, off, 64);
        sum2 += __shfl_down(sum2, off, 64);
    }
    const int lane = t & 63, wv = t >> 6;
    if (lane == 0) { lds[wv] = sum; lds[8 + wv] = sum2; }
    __syncthreads();
    if (t == 0) {
        float S1 = lds[0] + lds[1] + lds[2] + lds[3];
        float S2 = lds[8] + lds[9] + lds[10] + lds[11];
        float m = S1 * (1.0f / (float)HWN);
        float var = fmaf(-m, m, S2 * (1.0f / (float)HWN));
        float istd = rsqrtf(var + EPS_INST);
        float A = istd * (s0p + 1.0f);
        lds[12] = A;
        lds[13] = fmaf(-m, A, s1p);
    }
    __syncthreads();
    const float A = lds[12];
    const float Bs = lds[13];

    vf4* o4 = (vf4*)out + (size_t)(b * CC + c) * HW4;
#pragma unroll
    for (int i = 0; i < 4; ++i) {
        const int q = t + 256 * i;
        float4 zz = zv[i];
        vf4 o;
        o.x = fmaf(zz.x, A, Bs);
        o.y = fmaf(zz.y, A, Bs);
        o.z = fmaf(zz.z, A, Bs);
        o.w = fmaf(zz.w, A, Bs);
        __builtin_nontemporal_store(o, o4 + q);
    }
}

// ---------------------------------------------------------------------------
extern "C" void kernel_launch(void* const* d_in, const int* in_sizes, int n_in,
                              void* d_out, int out_size, void* d_ws, size_t ws_size,
                              hipStream_t stream) {
    const float* x      = (const float*)d_in[0];  // [16,512,64,64]
    const float* noise  = (const float*)d_in[1];  // [16,1,64,64]
    const float* style  = (const float*)d_in[2];  // [16,512]
    const float* nw     = (const float*)d_in[3];  // [512]
    const float* lin_W  = (const float*)d_in[4];  // [512,1024]
    const float* lin_b  = (const float*)d_in[5];  // [1024]
    float* out = (float*)d_out;
    float* ws  = (float*)d_ws;

    float* sp   = ws;             // style partials: 16*4*1024 = 65536 floats
    float* rbuf = ws + 65536;     // 16*4096 = 65536 floats

    k1_stats<<<NSTYLE + NPIX, 256, 0, stream>>>(
        x, noise, nw, style, lin_W, lin_b, rbuf, sp);
    fused_apply<<<BB * CC, 256, 0, stream>>>(x, noise, nw, rbuf, sp, out);
}